// Round 15
// baseline (229.575 us; speedup 1.0000x reference)
//
#include <hip/hip_runtime.h>
#include <hip/hip_bf16.h>

#define B_ 32
#define S_ 2048
#define D_ 1024
#define H_ 16
#define HD_ 64
#define MODES_ 16
#define EPS_ 1e-5f

#define NSPLIT_ 16
#define RPB_ 128        // rows per block (S / NSPLIT)
#define RPI_ 16         // rows per iteration
#define NIT_ (RPB_ / RPI_)

// workspace float offsets
#define OFF_CK      32            // B*H = 512
#define OFF_Q       1024          // B*D = 32768 fp32
#define OFF_QKBF    33792         // B*H*D bf16 = 262144 float-equiv
#define OFF_ML      295936        // 2 * NSPLIT*B*H = 16384 floats
#define ML_L_OFF    8192
#define OFF_PART_F  312320        // bf16 partials: NSPLIT*B*H*D ushorts = 4194304 float-equiv
#define OFF_CTX     4506624       // B*D
#define OFF_R1      4539392
#define OFF_Z1      4572160
#define OFF_ZSP     4604928
#define OFF_R2      4637696
#define OFF_Z3      4670464

typedef __attribute__((ext_vector_type(8))) short short8v;
typedef __attribute__((ext_vector_type(4))) float f32x4;

static __device__ inline ushort2 f2bf2(float a, float b) {
    __hip_bfloat162 h = __float22bfloat162_rn(make_float2(a, b));
    union { __hip_bfloat162 h; ushort2 u; } v; v.h = h; return v.u;
}
static __device__ inline unsigned short f2bf(float a) {
    __hip_bfloat16 h = __float2bfloat16(a);
    union { __hip_bfloat16 h; unsigned short u; } v; v.h = h; return v.u;
}
static __device__ inline float bf2f(unsigned s) {
    union { unsigned u; float f; } v; v.u = s << 16;
    return v.f;
}

// ---------------- q[b,n] = z_prev[b,:].Wq[n,:] + bq[n] ; ck[b,h] = q.bk ----------------
__global__ void k_q(const float* __restrict__ zprev, const float* __restrict__ ipw,
                    const float* __restrict__ ipb, float* __restrict__ q_out,
                    float* __restrict__ ck_out) {
    int b = blockIdx.x >> 2, nc = blockIdx.x & 3;
    __shared__ float zr[D_];
    int t = threadIdx.x;
    for (int i = t; i < D_; i += 256) zr[i] = zprev[(size_t)b * D_ + i];
    __syncthreads();
    int n = nc * 256 + t;
    const float4* wr = (const float4*)(ipw + (size_t)n * D_);
    float a0 = 0.f, a1 = 0.f, a2 = 0.f, a3 = 0.f;
    for (int k = 0; k < 256; k += 4) {
        float4 w0 = wr[k], w1 = wr[k + 1], w2 = wr[k + 2], w3 = wr[k + 3];
        float4 z0 = *(const float4*)&zr[4 * k];
        float4 z1 = *(const float4*)&zr[4 * k + 4];
        float4 z2 = *(const float4*)&zr[4 * k + 8];
        float4 z3 = *(const float4*)&zr[4 * k + 12];
        a0 = fmaf(z0.x, w0.x, a0); a0 = fmaf(z0.y, w0.y, a0); a0 = fmaf(z0.z, w0.z, a0); a0 = fmaf(z0.w, w0.w, a0);
        a1 = fmaf(z1.x, w1.x, a1); a1 = fmaf(z1.y, w1.y, a1); a1 = fmaf(z1.z, w1.z, a1); a1 = fmaf(z1.w, w1.w, a1);
        a2 = fmaf(z2.x, w2.x, a2); a2 = fmaf(z2.y, w2.y, a2); a2 = fmaf(z2.z, w2.z, a2); a2 = fmaf(z2.w, w2.w, a2);
        a3 = fmaf(z3.x, w3.x, a3); a3 = fmaf(z3.y, w3.y, a3); a3 = fmaf(z3.z, w3.z, a3); a3 = fmaf(z3.w, w3.w, a3);
    }
    float qv = (a0 + a1) + (a2 + a3) + ipb[n];
    q_out[(size_t)b * D_ + n] = qv;
    float cv = qv * ipb[D_ + n];
#pragma unroll
    for (int o = 32; o > 0; o >>= 1) cv += __shfl_xor(cv, o);
    if ((t & 63) == 0) ck_out[b * H_ + (n >> 6)] = cv;
}

// ---------------- qk[b,h,n] = sum_i q[b,h*64+i] * Wk[h*64+i, n] -> bf16 ----------------
__global__ void k_qkc(const float* __restrict__ ipw, const float* __restrict__ q_in,
                      unsigned short* __restrict__ qk_out) {
    int bid = blockIdx.x;
    int bc = bid & 3, nc = (bid >> 2) & 3, h = bid >> 4;
    int t = threadIdx.x;
    __shared__ float4 tile4[HD_ * 64];   // 64 rows x 256 cols = 64KB
    __shared__ float qall[8 * HD_];
    const float4* wk4 = (const float4*)(ipw + (size_t)D_ * D_);
#pragma unroll
    for (int j = 0; j < 16; ++j) {
        int lin4 = j * 256 + t;
        int i = lin4 >> 6, n4 = lin4 & 63;
        tile4[lin4] = wk4[(size_t)(h * HD_ + i) * 256 + nc * 64 + n4];
    }
#pragma unroll
    for (int j = 0; j < 2; ++j) {
        int idx = j * 256 + t;
        int bb = idx >> 6, i = idx & 63;
        qall[idx] = q_in[(size_t)(bc * 8 + bb) * D_ + h * HD_ + i];
    }
    __syncthreads();
    const float* tile = (const float*)tile4;
#pragma unroll
    for (int bb = 0; bb < 8; ++bb) {
        float a0 = 0.f, a1 = 0.f;
#pragma unroll
        for (int i = 0; i < HD_; i += 2) {
            a0 = fmaf(qall[bb * HD_ + i], tile[i * 256 + t], a0);
            a1 = fmaf(qall[bb * HD_ + i + 1], tile[(i + 1) * 256 + t], a1);
        }
        int b = bc * 8 + bb;
        qk_out[(size_t)(b * H_ + h) * D_ + nc * 256 + t] = f2bf(a0 + a1);
    }
}

// ---- fused attention, MFMA, dual-layout LDS, T14 register prefetch ----
__global__ __launch_bounds__(256, 2) void k_attn(const float* __restrict__ xfeat,
        const unsigned short* __restrict__ qkbf, const float* __restrict__ ck,
        unsigned short* __restrict__ part, float* __restrict__ ml) {
    int bid = blockIdx.x;
    int c = bid & (NSPLIT_ - 1), b = bid >> 4;
    int t = threadIdx.x, w = t >> 6, l = t & 63;
    __shared__ unsigned char xbuf[RPI_ * 2048];     // 32KB bf16 X rows, XOR-swizzled
    __shared__ unsigned char xcol[D_ * RPI_ * 2];   // 32KB bf16 X cols (d-major, slot-XOR)
    __shared__ float Sred[4][RPI_][17];             // padded
    __shared__ unsigned short Pt[16][32];           // P^T bf16; cols 16..31 stay ZERO
    __shared__ float mh[16], lh[16], fh[16], ckl[16];

    if (t < 16) { mh[t] = -1e30f; lh[t] = 0.f; ckl[t] = ck[b * H_ + t]; }
    // zero the padded upper-K half of Pt once (cols 16..31)
    {
        int h = t >> 4, s = 16 + (t & 15);
        Pt[h][s] = 0;
    }

    f32x4 acc[16];
#pragma unroll
    for (int nt = 0; nt < 16; ++nt) acc[nt] = (f32x4){0.f, 0.f, 0.f, 0.f};

    int hr = l & 15, kg = l >> 4;
    // hoist qk B-fragments (loop-invariant): 8 x 16B = 32 VGPRs
    const unsigned short* qkb = qkbf + ((size_t)(b * H_ + hr) << 10);
    short8v qfrag[8];
#pragma unroll
    for (int ks = 0; ks < 8; ++ks)
        qfrag[ks] = *(const short8v*)(qkb + w * 256 + ks * 32 + kg * 8);

    const float4* xbase = (const float4*)(xfeat + ((size_t)b * S_ + c * RPB_) * D_);
    // prologue: prefetch iter-0 tile into registers (16 float4/thread; LDS-bound so VGPR free)
    float4 cur[16];
#pragma unroll
    for (int j = 0; j < 16; ++j) cur[j] = xbase[j * 256 + t];

    for (int it = 0; it < NIT_; ++it) {
        __syncthreads();
        // ---- stage A: write prefetched tile -> bf16 row-major swizzled LDS ----
        {
#pragma unroll
            for (int j = 0; j < 16; ++j) {
                int idx = j * 256 + t;
                int row = idx >> 8, dq = idx & 255;
                unsigned off = (unsigned)(row * 2048 + dq * 8) ^ (unsigned)((row & 7) << 4);
                ushort2 lo = f2bf2(cur[j].x, cur[j].y), hi = f2bf2(cur[j].z, cur[j].w);
                ushort4 u; u.x = lo.x; u.y = lo.y; u.z = hi.x; u.w = hi.y;
                *(ushort4*)(xbuf + off) = u;
            }
        }
        // T14: issue next iter's global loads now; latency hides under phases 1-3
        if (it + 1 < NIT_) {
            const float4* src = xbase + (size_t)(it + 1) * (RPI_ * D_ / 4);
#pragma unroll
            for (int j = 0; j < 16; ++j) cur[j] = src[j * 256 + t];
        }
        __syncthreads();
        // ---- phase 1: S = X . qk^T ----
        {
            f32x4 s0 = {0.f, 0.f, 0.f, 0.f};
#pragma unroll
            for (int ks = 0; ks < 8; ++ks) {
                int k = w * 256 + ks * 32 + kg * 8;
                unsigned off0 = (unsigned)(hr * 2048 + k * 2) ^ (unsigned)((hr & 7) << 4);
                short8v a0 = *(const short8v*)(xbuf + off0);
                s0 = __builtin_amdgcn_mfma_f32_16x16x32_bf16(a0, qfrag[ks], s0, 0, 0, 0);
            }
            int rbase = kg * 4;
#pragma unroll
            for (int r = 0; r < 4; ++r) Sred[w][rbase + r][hr] = s0[r];
        }
        // ---- stage B (overlaps phase 1): transpose xbuf -> xcol ----
        {
#pragma unroll
            for (int i = 0; i < 16; ++i) {
                int rg = i & 3, d = (i >> 2) * 256 + t;
                unsigned cb = (unsigned)((d >> 2) * 8) + (unsigned)((d & 3) * 2);
                int r0 = rg * 4;
                unsigned short v0 = *(const unsigned short*)(xbuf + (((unsigned)((r0 + 0) * 2048) + cb) ^ (unsigned)(((r0 + 0) & 7) << 4)));
                unsigned short v1 = *(const unsigned short*)(xbuf + (((unsigned)((r0 + 1) * 2048) + cb) ^ (unsigned)(((r0 + 1) & 7) << 4)));
                unsigned short v2 = *(const unsigned short*)(xbuf + (((unsigned)((r0 + 2) * 2048) + cb) ^ (unsigned)(((r0 + 2) & 7) << 4)));
                unsigned short v3 = *(const unsigned short*)(xbuf + (((unsigned)((r0 + 3) * 2048) + cb) ^ (unsigned)(((r0 + 3) & 7) << 4)));
                ushort4 u; u.x = v0; u.y = v1; u.z = v2; u.w = v3;
                unsigned slot = (unsigned)((rg >> 1) ^ ((d >> 2) & 1));
                unsigned coff = (unsigned)(d * 32) + slot * 16 + (unsigned)((rg & 1) * 8);
                *(ushort4*)(xcol + coff) = u;
            }
        }
        __syncthreads();
        // ---- phase 2: softmax (one thread per (h,row)), online m/l across iters ----
        {
            int h = t >> 4, i16 = t & 15;
            float sv0 = Sred[0][i16][h] + Sred[1][i16][h] + Sred[2][i16][h] + Sred[3][i16][h];
            float s0 = (sv0 + ckl[h]) * 0.125f;
            float mm = s0;
#pragma unroll
            for (int o = 8; o > 0; o >>= 1) mm = fmaxf(mm, __shfl_xor(mm, o, 16));
            float mold = mh[h];
            float mnew = fmaxf(mold, mm);
            float p0 = __expf(s0 - mnew);
            Pt[h][i16] = f2bf(p0);
            float ps = p0;
#pragma unroll
            for (int o = 8; o > 0; o >>= 1) ps += __shfl_xor(ps, o, 16);
            if (i16 == 0) {
                float f = __expf(mold - mnew);
                fh[h] = f; lh[h] = lh[h] * f + ps; mh[h] = mnew;
            }
        }
        __syncthreads();
        // ---- phase 3: rescale acc, then O += P^T . X via MFMA, B-op = 1 b128 ----
        {
            float f0 = fh[kg * 4 + 0], f1 = fh[kg * 4 + 1], f2 = fh[kg * 4 + 2], f3 = fh[kg * 4 + 3];
#pragma unroll
            for (int nt = 0; nt < 16; ++nt) {
                acc[nt][0] *= f0; acc[nt][1] *= f1; acc[nt][2] *= f2; acc[nt][3] *= f3;
            }
            short8v pa = *(const short8v*)(&Pt[hr][kg * 8]);   // kg>=2 -> zeros
#pragma unroll
            for (int nt = 0; nt < 16; ++nt) {
                int d = w * 256 + nt * 16 + hr;
                unsigned coff = (unsigned)(d * 32) + (unsigned)((((kg & 1) ^ ((d >> 2) & 1)) << 4));
                short8v bx = *(const short8v*)(xcol + coff);
                acc[nt] = __builtin_amdgcn_mfma_f32_16x16x32_bf16(pa, bx, acc[nt], 0, 0, 0);
            }
        }
    }
    // ---- store bf16 partials + m/l ----
    {
#pragma unroll
        for (int nt = 0; nt < 16; ++nt) {
            int d = w * 256 + nt * 16 + hr;
#pragma unroll
            for (int r = 0; r < 4; ++r) {
                int h = kg * 4 + r;
                part[(((size_t)(c * B_ + b) * H_ + h) << 10) + d] = f2bf(acc[nt][r]);
            }
        }
        if (t < 16) {
            ml[(size_t)(c * B_ + b) * H_ + t] = mh[t];
            ml[ML_L_OFF + (size_t)(c * B_ + b) * H_ + t] = lh[t];
        }
    }
}

// ---------------- combine partials (16 splits) + ctx GEMV (Wv), merged ----------------
__global__ void k_ctx2(const float* __restrict__ ipw, const float* __restrict__ ipb,
                       const unsigned short* __restrict__ part, const float* __restrict__ ml,
                       float* __restrict__ ctx) {
    int b = blockIdx.x >> 2, nc = blockIdx.x & 3;
    int t = threadIdx.x;
    __shared__ float mls[4][16], lls[4][16], coef[4][16];
    __shared__ float xr[4 * D_];
    if (t < 64) {
        int h4 = t >> 4, c = t & 15;
        mls[h4][c] = ml[(size_t)(c * B_ + b) * H_ + nc * 4 + h4];
        lls[h4][c] = ml[ML_L_OFF + (size_t)(c * B_ + b) * H_ + nc * 4 + h4];
    }
    __syncthreads();
    if (t < 4) {
        float M = -1e30f;
        for (int c = 0; c < 16; ++c) M = fmaxf(M, mls[t][c]);
        float L = 0.f;
        for (int c = 0; c < 16; ++c) L += lls[t][c] * __expf(mls[t][c] - M);
        float invL = 1.f / L;
        for (int c = 0; c < 16; ++c) coef[t][c] = __expf(mls[t][c] - M) * invL;
    }
    __syncthreads();
    for (int idx = t * 2; idx < 4 * D_; idx += 512) {
        int h4 = idx >> 10, d = idx & 1023;
        int h = nc * 4 + h4;
        float a0 = 0.f, a1 = 0.f;
        for (int c = 0; c < 16; ++c) {
            unsigned u = *(const unsigned*)&part[(((size_t)(c * B_ + b) * H_ + h) << 10) + d];
            float cf = coef[h4][c];
            a0 = fmaf(bf2f(u & 0xffffu), cf, a0);
            a1 = fmaf(bf2f(u >> 16), cf, a1);
        }
        xr[idx] = a0; xr[idx + 1] = a1;
    }
    __syncthreads();
    int n = nc * 256 + t;
    int hl = t >> 6;
    const float4* wr = (const float4*)(ipw + ((size_t)2 * D_ + n) * D_);
    const float4* xv4 = (const float4*)&xr[hl * D_];
    float a0 = 0.f, a1 = 0.f, a2 = 0.f, a3 = 0.f;
    for (int k = 0; k < 256; k += 4) {
        float4 w0 = wr[k], w1 = wr[k + 1], w2 = wr[k + 2], w3 = wr[k + 3];
        float4 x0 = xv4[k], x1 = xv4[k + 1], x2 = xv4[k + 2], x3 = xv4[k + 3];
        a0 = fmaf(w0.x, x0.x, a0); a0 = fmaf(w0.y, x0.y, a0); a0 = fmaf(w0.z, x0.z, a0); a0 = fmaf(w0.w, x0.w, a0);
        a1 = fmaf(w1.x, x1.x, a1); a1 = fmaf(w1.y, x1.y, a1); a1 = fmaf(w1.z, x1.z, a1); a1 = fmaf(w1.w, x1.w, a1);
        a2 = fmaf(w2.x, x2.x, a2); a2 = fmaf(w2.y, x2.y, a2); a2 = fmaf(w2.z, x2.z, a2); a2 = fmaf(w2.w, x2.w, a2);
        a3 = fmaf(w3.x, x3.x, a3); a3 = fmaf(w3.y, x3.y, a3); a3 = fmaf(w3.z, x3.z, a3); a3 = fmaf(w3.w, x3.w, a3);
    }
    ctx[(size_t)b * D_ + n] = (a0 + a1) + (a2 + a3) + ipb[2 * D_ + n];
}

// ---------------- out = resid + scale*(invec @ W.T + bias) ----------------
__global__ void k_proj_res(const float* __restrict__ wmat, const float* __restrict__ bias,
                           const float* __restrict__ scale, const float* __restrict__ resid,
                           const float* __restrict__ invec, float* __restrict__ outvec) {
    int b = blockIdx.x >> 2, nc = blockIdx.x & 3;
    __shared__ float cx[D_];
    int t = threadIdx.x;
    for (int i = t; i < D_; i += 256) cx[i] = invec[(size_t)b * D_ + i];
    __syncthreads();
    int n = nc * 256 + t;
    const float4* wr = (const float4*)(wmat + (size_t)n * D_);
    float a0 = 0.f, a1 = 0.f, a2 = 0.f, a3 = 0.f;
    for (int k = 0; k < 256; k += 4) {
        float4 w0 = wr[k], w1 = wr[k + 1], w2 = wr[k + 2], w3 = wr[k + 3];
        float4 c0 = *(const float4*)&cx[4 * k];
        float4 c1 = *(const float4*)&cx[4 * k + 4];
        float4 c2 = *(const float4*)&cx[4 * k + 8];
        float4 c3 = *(const float4*)&cx[4 * k + 12];
        a0 = fmaf(w0.x, c0.x, a0); a0 = fmaf(w0.y, c0.y, a0); a0 = fmaf(w0.z, c0.z, a0); a0 = fmaf(w0.w, c0.w, a0);
        a1 = fmaf(w1.x, c1.x, a1); a1 = fmaf(w1.y, c1.y, a1); a1 = fmaf(w1.z, c1.z, a1); a1 = fmaf(w1.w, c1.w, a1);
        a2 = fmaf(w2.x, c2.x, a2); a2 = fmaf(w2.y, c2.y, a2); a2 = fmaf(w2.z, c2.z, a2); a2 = fmaf(w2.w, c2.w, a2);
        a3 = fmaf(w3.x, c3.x, a3); a3 = fmaf(w3.y, c3.y, a3); a3 = fmaf(w3.z, c3.z, a3); a3 = fmaf(w3.w, c3.w, a3);
    }
    float acc = (a0 + a1) + (a2 + a3);
    outvec[(size_t)b * D_ + n] = resid[(size_t)b * D_ + n] + scale[0] * (acc + bias[n]);
}

// ---------------- fused LN1 + spectral (filt, DFT, filter, synthesize) ----------------
__global__ void k_lnspec(const float* __restrict__ r1, const float* __restrict__ g1,
                         const float* __restrict__ b1, const float* __restrict__ sreal,
                         const float* __restrict__ simag, float* __restrict__ z1out,
                         float* __restrict__ zspout) {
    int b = blockIdx.x, t = threadIdx.x, w = t >> 6, l = t & 63;
    __shared__ float zr[D_];
    __shared__ float fre[MODES_], fim[MODES_];
    __shared__ float cre[MODES_], cim[MODES_];
    __shared__ float sa[4], sb[4];
    float4 v = ((const float4*)(r1 + (size_t)b * D_))[t];
    float s = v.x + v.y + v.z + v.w;
    float s2 = v.x * v.x + v.y * v.y + v.z * v.z + v.w * v.w;
#pragma unroll
    for (int o = 32; o > 0; o >>= 1) { s += __shfl_xor(s, o); s2 += __shfl_xor(s2, o); }
    if (l == 0) { sa[w] = s; sb[w] = s2; }
    int m = t >> 4, sub = t & 15;
    {
        float ar = 0.f, ai = 0.f;
        for (int k = sub; k < D_; k += 16) { ar += sreal[m * D_ + k]; ai += simag[m * D_ + k]; }
#pragma unroll
        for (int o = 8; o > 0; o >>= 1) { ar += __shfl_xor(ar, o, 16); ai += __shfl_xor(ai, o, 16); }
        if (sub == 0) { fre[m] = ar * (1.f / (float)D_); fim[m] = ai * (1.f / (float)D_); }
    }
    __syncthreads();
    s = sa[0] + sa[1] + sa[2] + sa[3];
    s2 = sb[0] + sb[1] + sb[2] + sb[3];
    float mu = s * (1.f / (float)D_);
    float var = s2 * (1.f / (float)D_) - mu * mu;
    float rs = rsqrtf(var + EPS_);
    float4 gg = ((const float4*)g1)[t], bbv = ((const float4*)b1)[t];
    float4 z4;
    z4.x = (v.x - mu) * rs * gg.x + bbv.x;
    z4.y = (v.y - mu) * rs * gg.y + bbv.y;
    z4.z = (v.z - mu) * rs * gg.z + bbv.z;
    z4.w = (v.w - mu) * rs * gg.w + bbv.w;
    ((float4*)(z1out + (size_t)b * D_))[t] = z4;
    *(float4*)&zr[4 * t] = z4;
    __syncthreads();
    const float step = 6.283185307179586f / (float)D_;
    {
        float ar = 0.f, ai = 0.f;
        for (int n = sub; n < D_; n += 16) {
            int idx = (m * n) & (D_ - 1);
            float sn, cs;
            __sincosf(step * (float)idx, &sn, &cs);
            float z = zr[n];
            ar = fmaf(z, cs, ar); ai = fmaf(-z, sn, ai);
        }
#pragma unroll
        for (int o = 8; o > 0; o >>= 1) { ar += __shfl_xor(ar, o, 16); ai += __shfl_xor(ai, o, 16); }
        if (sub == 0) {
            cre[m] = (fre[m] * ar - fim[m] * ai) * (1.f / (float)D_);
            cim[m] = (fre[m] * ai + fim[m] * ar) * (1.f / (float)D_);
        }
    }
    __syncthreads();
    for (int n = t; n < D_; n += 256) {
        float acc = 0.f;
#pragma unroll
        for (int mm = 0; mm < MODES_; ++mm) {
            int idx = (mm * n) & (D_ - 1);
            float sn, cs;
            __sincosf(step * (float)idx, &sn, &cs);
            acc += cre[mm] * cs - cim[mm] * sn;
        }
        zspout[(size_t)b * D_ + n] = acc;
    }
}

// ---------------- LN2 + gate mix -> z3 ----------------
__global__ void k_ln2gate(const float* __restrict__ zprev, const float* __restrict__ g2,
                          const float* __restrict__ b2v, const float* __restrict__ gate,
                          float* __restrict__ ws) {
    int b = blockIdx.x, t = threadIdx.x, w = t >> 6, l = t & 63;
    float4 v = ((const float4*)(ws + OFF_R2 + (size_t)b * D_))[t];
    float s = v.x + v.y + v.z + v.w;
    float s2 = v.x * v.x + v.y * v.y + v.z * v.z + v.w * v.w;
    __shared__ float sa[4], sb[4];
#pragma unroll
    for (int o = 32; o > 0; o >>= 1) { s += __shfl_xor(s, o); s2 += __shfl_xor(s2, o); }
    if (l == 0) { sa[w] = s; sb[w] = s2; }
    __syncthreads();
    s = sa[0] + sa[1] + sa[2] + sa[3];
    s2 = sb[0] + sb[1] + sb[2] + sb[3];
    float mu = s * (1.f / (float)D_);
    float var = s2 * (1.f / (float)D_) - mu * mu;
    float rs = rsqrtf(var + EPS_);
    float4 gg = ((const float4*)g2)[t], bb = ((const float4*)b2v)[t];
    float gsig = 1.f / (1.f + __expf(-gate[0]));
    float4 zp = ((const float4*)(zprev + (size_t)b * D_))[t];
    float4 z3;
    z3.x = gsig * ((v.x - mu) * rs * gg.x + bb.x) + (1.f - gsig) * zp.x;
    z3.y = gsig * ((v.y - mu) * rs * gg.y + bb.y) + (1.f - gsig) * zp.y;
    z3.z = gsig * ((v.z - mu) * rs * gg.z + bb.z) + (1.f - gsig) * zp.z;
    z3.w = gsig * ((v.w - mu) * rs * gg.w + bb.w) + (1.f - gsig) * zp.w;
    ((float4*)(ws + OFF_Z3 + (size_t)b * D_))[t] = z3;
}

// ---------------- batchnorm over B per column ----------------
__global__ void k_bn(const float* __restrict__ bng, const float* __restrict__ bnb,
                     const float* __restrict__ z3, float* __restrict__ out) {
    int d = blockIdx.x * 256 + threadIdx.x;
    float vals[B_];
    float s = 0.f, s2 = 0.f;
#pragma unroll
    for (int b = 0; b < B_; ++b) {
        float v = z3[(size_t)b * D_ + d];
        vals[b] = v; s += v; s2 = fmaf(v, v, s2);
    }
    float mu = s * (1.f / (float)B_);
    float var = s2 * (1.f / (float)B_) - mu * mu;
    float rs = rsqrtf(var + EPS_);
    float gg = bng[d], bb = bnb[d];
#pragma unroll
    for (int b = 0; b < B_; ++b) out[(size_t)b * D_ + d] = (vals[b] - mu) * rs * gg + bb;
}

extern "C" void kernel_launch(void* const* d_in, const int* in_sizes, int n_in,
                              void* d_out, int out_size, void* d_ws, size_t ws_size,
                              hipStream_t stream) {
    const float* x_feat = (const float*)d_in[0];
    const float* z_prev = (const float*)d_in[1];
    const float* ipw    = (const float*)d_in[2];
    const float* ipb    = (const float*)d_in[3];
    const float* wout   = (const float*)d_in[4];
    const float* bout   = (const float*)d_in[5];
    const float* ln1g   = (const float*)d_in[6];
    const float* ln1b   = (const float*)d_in[7];
    const float* ln2g   = (const float*)d_in[8];
    const float* ln2b   = (const float*)d_in[9];
    const float* sreal  = (const float*)d_in[10];
    const float* simag  = (const float*)d_in[11];
    const float* pw     = (const float*)d_in[12];
    const float* pb     = (const float*)d_in[13];
    const float* bng    = (const float*)d_in[14];
    const float* bnb    = (const float*)d_in[15];
    const float* gate   = (const float*)d_in[16];
    const float* sattn  = (const float*)d_in[17];
    const float* sden   = (const float*)d_in[18];
    float* ws  = (float*)d_ws;
    float* out = (float*)d_out;
    unsigned short* qkbf  = (unsigned short*)(ws + OFF_QKBF);
    unsigned short* partp = (unsigned short*)(ws + OFF_PART_F);

    k_q<<<B_ * 4, 256, 0, stream>>>(z_prev, ipw, ipb, ws + OFF_Q, ws + OFF_CK);
    k_qkc<<<H_ * 16, 256, 0, stream>>>(ipw, ws + OFF_Q, qkbf);
    k_attn<<<B_ * NSPLIT_, 256, 0, stream>>>(x_feat, qkbf, ws + OFF_CK, partp, ws + OFF_ML);
    k_ctx2<<<B_ * 4, 256, 0, stream>>>(ipw, ipb, partp, ws + OFF_ML, ws + OFF_CTX);
    k_proj_res<<<B_ * 4, 256, 0, stream>>>(wout, bout, sattn, z_prev, ws + OFF_CTX, ws + OFF_R1);
    k_lnspec<<<B_, 256, 0, stream>>>(ws + OFF_R1, ln1g, ln1b, sreal, simag,
                                     ws + OFF_Z1, ws + OFF_ZSP);
    k_proj_res<<<B_ * 4, 256, 0, stream>>>(pw, pb, sden, ws + OFF_Z1, ws + OFF_ZSP, ws + OFF_R2);
    k_ln2gate<<<B_, 256, 0, stream>>>(z_prev, ln2g, ln2b, gate, ws);
    k_bn<<<D_ / 256, 256, 0, stream>>>(bng, bnb, ws + OFF_Z3, out);
}

// Round 16
// 227.586 us; speedup vs baseline: 1.0087x; 1.0087x over previous
//
#include <hip/hip_runtime.h>
#include <hip/hip_bf16.h>

#define B_ 32
#define S_ 2048
#define D_ 1024
#define H_ 16
#define HD_ 64
#define MODES_ 16
#define EPS_ 1e-5f

#define NSPLIT_ 16
#define RPB_ 128        // rows per block (S / NSPLIT)
#define RPI_ 16         // rows per iteration
#define NIT_ (RPB_ / RPI_)

// workspace float offsets
#define OFF_CK      32            // B*H = 512
#define OFF_Q       1024          // B*D = 32768 fp32
#define OFF_QKBF    33792         // B*H*D bf16 = 262144 float-equiv
#define OFF_ML      295936        // 2 * NSPLIT*B*H = 16384 floats
#define ML_L_OFF    8192
#define OFF_PART_F  312320        // bf16 partials: NSPLIT*B*H*D ushorts = 4194304 float-equiv
#define OFF_CTX     4506624       // B*D
#define OFF_R1      4539392
#define OFF_Z1      4572160
#define OFF_ZSP     4604928
#define OFF_R2      4637696
#define OFF_Z3      4670464

typedef __attribute__((ext_vector_type(8))) short short8v;
typedef __attribute__((ext_vector_type(4))) float f32x4;

static __device__ inline ushort2 f2bf2(float a, float b) {
    __hip_bfloat162 h = __float22bfloat162_rn(make_float2(a, b));
    union { __hip_bfloat162 h; ushort2 u; } v; v.h = h; return v.u;
}
static __device__ inline unsigned short f2bf(float a) {
    __hip_bfloat16 h = __float2bfloat16(a);
    union { __hip_bfloat16 h; unsigned short u; } v; v.h = h; return v.u;
}
static __device__ inline float bf2f(unsigned s) {
    union { unsigned u; float f; } v; v.u = s << 16;
    return v.f;
}

// ---------------- q[b,n] = z_prev[b,:].Wq[n,:] + bq[n] ; ck[b,h] = q.bk ----------------
__global__ void k_q(const float* __restrict__ zprev, const float* __restrict__ ipw,
                    const float* __restrict__ ipb, float* __restrict__ q_out,
                    float* __restrict__ ck_out) {
    int b = blockIdx.x >> 2, nc = blockIdx.x & 3;
    __shared__ float zr[D_];
    int t = threadIdx.x;
    for (int i = t; i < D_; i += 256) zr[i] = zprev[(size_t)b * D_ + i];
    __syncthreads();
    int n = nc * 256 + t;
    const float4* wr = (const float4*)(ipw + (size_t)n * D_);
    float a0 = 0.f, a1 = 0.f, a2 = 0.f, a3 = 0.f;
    for (int k = 0; k < 256; k += 4) {
        float4 w0 = wr[k], w1 = wr[k + 1], w2 = wr[k + 2], w3 = wr[k + 3];
        float4 z0 = *(const float4*)&zr[4 * k];
        float4 z1 = *(const float4*)&zr[4 * k + 4];
        float4 z2 = *(const float4*)&zr[4 * k + 8];
        float4 z3 = *(const float4*)&zr[4 * k + 12];
        a0 = fmaf(z0.x, w0.x, a0); a0 = fmaf(z0.y, w0.y, a0); a0 = fmaf(z0.z, w0.z, a0); a0 = fmaf(z0.w, w0.w, a0);
        a1 = fmaf(z1.x, w1.x, a1); a1 = fmaf(z1.y, w1.y, a1); a1 = fmaf(z1.z, w1.z, a1); a1 = fmaf(z1.w, w1.w, a1);
        a2 = fmaf(z2.x, w2.x, a2); a2 = fmaf(z2.y, w2.y, a2); a2 = fmaf(z2.z, w2.z, a2); a2 = fmaf(z2.w, w2.w, a2);
        a3 = fmaf(z3.x, w3.x, a3); a3 = fmaf(z3.y, w3.y, a3); a3 = fmaf(z3.z, w3.z, a3); a3 = fmaf(z3.w, w3.w, a3);
    }
    float qv = (a0 + a1) + (a2 + a3) + ipb[n];
    q_out[(size_t)b * D_ + n] = qv;
    float cv = qv * ipb[D_ + n];
#pragma unroll
    for (int o = 32; o > 0; o >>= 1) cv += __shfl_xor(cv, o);
    if ((t & 63) == 0) ck_out[b * H_ + (n >> 6)] = cv;
}

// ---------------- qk[b,h,n] = sum_i q[b,h*64+i] * Wk[h*64+i, n] -> bf16 ----------------
__global__ void k_qkc(const float* __restrict__ ipw, const float* __restrict__ q_in,
                      unsigned short* __restrict__ qk_out) {
    int bid = blockIdx.x;
    int bc = bid & 3, nc = (bid >> 2) & 3, h = bid >> 4;
    int t = threadIdx.x;
    __shared__ float4 tile4[HD_ * 64];   // 64 rows x 256 cols = 64KB
    __shared__ float qall[8 * HD_];
    const float4* wk4 = (const float4*)(ipw + (size_t)D_ * D_);
#pragma unroll
    for (int j = 0; j < 16; ++j) {
        int lin4 = j * 256 + t;
        int i = lin4 >> 6, n4 = lin4 & 63;
        tile4[lin4] = wk4[(size_t)(h * HD_ + i) * 256 + nc * 64 + n4];
    }
#pragma unroll
    for (int j = 0; j < 2; ++j) {
        int idx = j * 256 + t;
        int bb = idx >> 6, i = idx & 63;
        qall[idx] = q_in[(size_t)(bc * 8 + bb) * D_ + h * HD_ + i];
    }
    __syncthreads();
    const float* tile = (const float*)tile4;
#pragma unroll
    for (int bb = 0; bb < 8; ++bb) {
        float a0 = 0.f, a1 = 0.f;
#pragma unroll
        for (int i = 0; i < HD_; i += 2) {
            a0 = fmaf(qall[bb * HD_ + i], tile[i * 256 + t], a0);
            a1 = fmaf(qall[bb * HD_ + i + 1], tile[(i + 1) * 256 + t], a1);
        }
        int b = bc * 8 + bb;
        qk_out[(size_t)(b * H_ + h) * D_ + nc * 256 + t] = f2bf(a0 + a1);
    }
}

// ---- fused attention, MFMA, dual-layout LDS: row-major xbuf (QK^T A-op) +
// ---- d-major xcol (PV B-op as single b128 per MFMA, no scalar gather) ----
__global__ __launch_bounds__(256, 2) void k_attn(const float* __restrict__ xfeat,
        const unsigned short* __restrict__ qkbf, const float* __restrict__ ck,
        unsigned short* __restrict__ part, float* __restrict__ ml) {
    int bid = blockIdx.x;
    int c = bid & (NSPLIT_ - 1), b = bid >> 4;
    int t = threadIdx.x, w = t >> 6, l = t & 63;
    __shared__ unsigned char xbuf[RPI_ * 2048];     // 32KB bf16 X rows, XOR-swizzled
    __shared__ unsigned char xcol[D_ * RPI_ * 2];   // 32KB bf16 X cols (d-major, slot-XOR)
    __shared__ float Sred[4][RPI_][17];             // padded
    __shared__ unsigned short Pt[16][32];           // P^T bf16; cols 16..31 stay ZERO
    __shared__ float mh[16], lh[16], fh[16], ckl[16];

    if (t < 16) { mh[t] = -1e30f; lh[t] = 0.f; ckl[t] = ck[b * H_ + t]; }
    // zero the padded upper-K half of Pt once (cols 16..31)
    {
        int h = t >> 4, s = 16 + (t & 15);
        Pt[h][s] = 0;
    }

    f32x4 acc[16];
#pragma unroll
    for (int nt = 0; nt < 16; ++nt) acc[nt] = (f32x4){0.f, 0.f, 0.f, 0.f};

    int hr = l & 15, kg = l >> 4;
    // hoist qk B-fragments (loop-invariant): 8 x 16B = 32 VGPRs
    const unsigned short* qkb = qkbf + ((size_t)(b * H_ + hr) << 10);
    short8v qfrag[8];
#pragma unroll
    for (int ks = 0; ks < 8; ++ks)
        qfrag[ks] = *(const short8v*)(qkb + w * 256 + ks * 32 + kg * 8);

    for (int it = 0; it < NIT_; ++it) {
        __syncthreads();
        // ---- stage A: 16 rows fp32 -> bf16 row-major swizzled LDS ----
        {
            const float4* src = (const float4*)(xfeat + ((size_t)b * S_ + c * RPB_ + it * RPI_) * D_);
#pragma unroll
            for (int j = 0; j < 16; ++j) {
                int idx = j * 256 + t;
                float4 v = src[idx];
                int row = idx >> 8, dq = idx & 255;
                unsigned off = (unsigned)(row * 2048 + dq * 8) ^ (unsigned)((row & 7) << 4);
                ushort2 lo = f2bf2(v.x, v.y), hi = f2bf2(v.z, v.w);
                ushort4 u; u.x = lo.x; u.y = lo.y; u.z = hi.x; u.w = hi.y;
                *(ushort4*)(xbuf + off) = u;
            }
        }
        __syncthreads();
        // ---- phase 1: S = X . qk^T ----
        {
            f32x4 s0 = {0.f, 0.f, 0.f, 0.f};
#pragma unroll
            for (int ks = 0; ks < 8; ++ks) {
                int k = w * 256 + ks * 32 + kg * 8;
                unsigned off0 = (unsigned)(hr * 2048 + k * 2) ^ (unsigned)((hr & 7) << 4);
                short8v a0 = *(const short8v*)(xbuf + off0);
                s0 = __builtin_amdgcn_mfma_f32_16x16x32_bf16(a0, qfrag[ks], s0, 0, 0, 0);
            }
            int rbase = kg * 4;
#pragma unroll
            for (int r = 0; r < 4; ++r) Sred[w][rbase + r][hr] = s0[r];
        }
        // ---- stage B (overlaps phase 1): transpose xbuf -> xcol ----
        // strip i: rows rg*4..rg*4+3 at col d; xcol slot-XOR: slot=(rg>>1)^((d>>2)&1)
        {
#pragma unroll
            for (int i = 0; i < 16; ++i) {
                int rg = i & 3, d = (i >> 2) * 256 + t;
                unsigned cb = (unsigned)((d >> 2) * 8) + (unsigned)((d & 3) * 2);
                int r0 = rg * 4;
                unsigned short v0 = *(const unsigned short*)(xbuf + (((unsigned)((r0 + 0) * 2048) + cb) ^ (unsigned)(((r0 + 0) & 7) << 4)));
                unsigned short v1 = *(const unsigned short*)(xbuf + (((unsigned)((r0 + 1) * 2048) + cb) ^ (unsigned)(((r0 + 1) & 7) << 4)));
                unsigned short v2 = *(const unsigned short*)(xbuf + (((unsigned)((r0 + 2) * 2048) + cb) ^ (unsigned)(((r0 + 2) & 7) << 4)));
                unsigned short v3 = *(const unsigned short*)(xbuf + (((unsigned)((r0 + 3) * 2048) + cb) ^ (unsigned)(((r0 + 3) & 7) << 4)));
                ushort4 u; u.x = v0; u.y = v1; u.z = v2; u.w = v3;
                unsigned slot = (unsigned)((rg >> 1) ^ ((d >> 2) & 1));
                unsigned coff = (unsigned)(d * 32) + slot * 16 + (unsigned)((rg & 1) * 8);
                *(ushort4*)(xcol + coff) = u;
            }
        }
        __syncthreads();
        // ---- phase 2: softmax (one thread per (h,row)), online m/l across iters ----
        {
            int h = t >> 4, i16 = t & 15;
            float sv0 = Sred[0][i16][h] + Sred[1][i16][h] + Sred[2][i16][h] + Sred[3][i16][h];
            float s0 = (sv0 + ckl[h]) * 0.125f;
            float mm = s0;
#pragma unroll
            for (int o = 8; o > 0; o >>= 1) mm = fmaxf(mm, __shfl_xor(mm, o, 16));
            float mold = mh[h];
            float mnew = fmaxf(mold, mm);
            float p0 = __expf(s0 - mnew);
            Pt[h][i16] = f2bf(p0);
            float ps = p0;
#pragma unroll
            for (int o = 8; o > 0; o >>= 1) ps += __shfl_xor(ps, o, 16);
            if (i16 == 0) {
                float f = __expf(mold - mnew);
                fh[h] = f; lh[h] = lh[h] * f + ps; mh[h] = mnew;
            }
        }
        __syncthreads();
        // ---- phase 3: rescale acc, then O += P^T . X via MFMA, B-op = 1 b128 ----
        {
            float f0 = fh[kg * 4 + 0], f1 = fh[kg * 4 + 1], f2 = fh[kg * 4 + 2], f3 = fh[kg * 4 + 3];
#pragma unroll
            for (int nt = 0; nt < 16; ++nt) {
                acc[nt][0] *= f0; acc[nt][1] *= f1; acc[nt][2] *= f2; acc[nt][3] *= f3;
            }
            short8v pa = *(const short8v*)(&Pt[hr][kg * 8]);   // kg>=2 -> zeros
#pragma unroll
            for (int nt = 0; nt < 16; ++nt) {
                int d = w * 256 + nt * 16 + hr;
                unsigned coff = (unsigned)(d * 32) + (unsigned)((((kg & 1) ^ ((d >> 2) & 1)) << 4));
                short8v bx = *(const short8v*)(xcol + coff);
                acc[nt] = __builtin_amdgcn_mfma_f32_16x16x32_bf16(pa, bx, acc[nt], 0, 0, 0);
            }
        }
    }
    // ---- store bf16 partials + m/l ----
    {
#pragma unroll
        for (int nt = 0; nt < 16; ++nt) {
            int d = w * 256 + nt * 16 + hr;
#pragma unroll
            for (int r = 0; r < 4; ++r) {
                int h = kg * 4 + r;
                part[(((size_t)(c * B_ + b) * H_ + h) << 10) + d] = f2bf(acc[nt][r]);
            }
        }
        if (t < 16) {
            ml[(size_t)(c * B_ + b) * H_ + t] = mh[t];
            ml[ML_L_OFF + (size_t)(c * B_ + b) * H_ + t] = lh[t];
        }
    }
}

// ---------------- combine partials (16 splits) + ctx GEMV (Wv), merged ----------------
__global__ void k_ctx2(const float* __restrict__ ipw, const float* __restrict__ ipb,
                       const unsigned short* __restrict__ part, const float* __restrict__ ml,
                       float* __restrict__ ctx) {
    int b = blockIdx.x >> 2, nc = blockIdx.x & 3;
    int t = threadIdx.x;
    __shared__ float mls[4][16], lls[4][16], coef[4][16];
    __shared__ float xr[4 * D_];
    if (t < 64) {
        int h4 = t >> 4, c = t & 15;
        mls[h4][c] = ml[(size_t)(c * B_ + b) * H_ + nc * 4 + h4];
        lls[h4][c] = ml[ML_L_OFF + (size_t)(c * B_ + b) * H_ + nc * 4 + h4];
    }
    __syncthreads();
    if (t < 4) {
        float M = -1e30f;
        for (int c = 0; c < 16; ++c) M = fmaxf(M, mls[t][c]);
        float L = 0.f;
        for (int c = 0; c < 16; ++c) L += lls[t][c] * __expf(mls[t][c] - M);
        float invL = 1.f / L;
        for (int c = 0; c < 16; ++c) coef[t][c] = __expf(mls[t][c] - M) * invL;
    }
    __syncthreads();
    for (int idx = t * 2; idx < 4 * D_; idx += 512) {
        int h4 = idx >> 10, d = idx & 1023;
        int h = nc * 4 + h4;
        float a0 = 0.f, a1 = 0.f;
        for (int c = 0; c < 16; ++c) {
            unsigned u = *(const unsigned*)&part[(((size_t)(c * B_ + b) * H_ + h) << 10) + d];
            float cf = coef[h4][c];
            a0 = fmaf(bf2f(u & 0xffffu), cf, a0);
            a1 = fmaf(bf2f(u >> 16), cf, a1);
        }
        xr[idx] = a0; xr[idx + 1] = a1;
    }
    __syncthreads();
    int n = nc * 256 + t;
    int hl = t >> 6;
    const float4* wr = (const float4*)(ipw + ((size_t)2 * D_ + n) * D_);
    const float4* xv4 = (const float4*)&xr[hl * D_];
    float a0 = 0.f, a1 = 0.f, a2 = 0.f, a3 = 0.f;
    for (int k = 0; k < 256; k += 4) {
        float4 w0 = wr[k], w1 = wr[k + 1], w2 = wr[k + 2], w3 = wr[k + 3];
        float4 x0 = xv4[k], x1 = xv4[k + 1], x2 = xv4[k + 2], x3 = xv4[k + 3];
        a0 = fmaf(w0.x, x0.x, a0); a0 = fmaf(w0.y, x0.y, a0); a0 = fmaf(w0.z, x0.z, a0); a0 = fmaf(w0.w, x0.w, a0);
        a1 = fmaf(w1.x, x1.x, a1); a1 = fmaf(w1.y, x1.y, a1); a1 = fmaf(w1.z, x1.z, a1); a1 = fmaf(w1.w, x1.w, a1);
        a2 = fmaf(w2.x, x2.x, a2); a2 = fmaf(w2.y, x2.y, a2); a2 = fmaf(w2.z, x2.z, a2); a2 = fmaf(w2.w, x2.w, a2);
        a3 = fmaf(w3.x, x3.x, a3); a3 = fmaf(w3.y, x3.y, a3); a3 = fmaf(w3.z, x3.z, a3); a3 = fmaf(w3.w, x3.w, a3);
    }
    ctx[(size_t)b * D_ + n] = (a0 + a1) + (a2 + a3) + ipb[2 * D_ + n];
}

// ---------------- out = resid + scale*(invec @ W.T + bias) ----------------
__global__ void k_proj_res(const float* __restrict__ wmat, const float* __restrict__ bias,
                           const float* __restrict__ scale, const float* __restrict__ resid,
                           const float* __restrict__ invec, float* __restrict__ outvec) {
    int b = blockIdx.x >> 2, nc = blockIdx.x & 3;
    __shared__ float cx[D_];
    int t = threadIdx.x;
    for (int i = t; i < D_; i += 256) cx[i] = invec[(size_t)b * D_ + i];
    __syncthreads();
    int n = nc * 256 + t;
    const float4* wr = (const float4*)(wmat + (size_t)n * D_);
    float a0 = 0.f, a1 = 0.f, a2 = 0.f, a3 = 0.f;
    for (int k = 0; k < 256; k += 4) {
        float4 w0 = wr[k], w1 = wr[k + 1], w2 = wr[k + 2], w3 = wr[k + 3];
        float4 c0 = *(const float4*)&cx[4 * k];
        float4 c1 = *(const float4*)&cx[4 * k + 4];
        float4 c2 = *(const float4*)&cx[4 * k + 8];
        float4 c3 = *(const float4*)&cx[4 * k + 12];
        a0 = fmaf(w0.x, c0.x, a0); a0 = fmaf(w0.y, c0.y, a0); a0 = fmaf(w0.z, c0.z, a0); a0 = fmaf(w0.w, c0.w, a0);
        a1 = fmaf(w1.x, c1.x, a1); a1 = fmaf(w1.y, c1.y, a1); a1 = fmaf(w1.z, c1.z, a1); a1 = fmaf(w1.w, c1.w, a1);
        a2 = fmaf(w2.x, c2.x, a2); a2 = fmaf(w2.y, c2.y, a2); a2 = fmaf(w2.z, c2.z, a2); a2 = fmaf(w2.w, c2.w, a2);
        a3 = fmaf(w3.x, c3.x, a3); a3 = fmaf(w3.y, c3.y, a3); a3 = fmaf(w3.z, c3.z, a3); a3 = fmaf(w3.w, c3.w, a3);
    }
    float acc = (a0 + a1) + (a2 + a3);
    outvec[(size_t)b * D_ + n] = resid[(size_t)b * D_ + n] + scale[0] * (acc + bias[n]);
}

// ---------------- fused LN1 + spectral (filt, DFT, filter, synthesize) ----------------
__global__ void k_lnspec(const float* __restrict__ r1, const float* __restrict__ g1,
                         const float* __restrict__ b1, const float* __restrict__ sreal,
                         const float* __restrict__ simag, float* __restrict__ z1out,
                         float* __restrict__ zspout) {
    int b = blockIdx.x, t = threadIdx.x, w = t >> 6, l = t & 63;
    __shared__ float zr[D_];
    __shared__ float fre[MODES_], fim[MODES_];
    __shared__ float cre[MODES_], cim[MODES_];
    __shared__ float sa[4], sb[4];
    float4 v = ((const float4*)(r1 + (size_t)b * D_))[t];
    float s = v.x + v.y + v.z + v.w;
    float s2 = v.x * v.x + v.y * v.y + v.z * v.z + v.w * v.w;
#pragma unroll
    for (int o = 32; o > 0; o >>= 1) { s += __shfl_xor(s, o); s2 += __shfl_xor(s2, o); }
    if (l == 0) { sa[w] = s; sb[w] = s2; }
    int m = t >> 4, sub = t & 15;
    {
        float ar = 0.f, ai = 0.f;
        for (int k = sub; k < D_; k += 16) { ar += sreal[m * D_ + k]; ai += simag[m * D_ + k]; }
#pragma unroll
        for (int o = 8; o > 0; o >>= 1) { ar += __shfl_xor(ar, o, 16); ai += __shfl_xor(ai, o, 16); }
        if (sub == 0) { fre[m] = ar * (1.f / (float)D_); fim[m] = ai * (1.f / (float)D_); }
    }
    __syncthreads();
    s = sa[0] + sa[1] + sa[2] + sa[3];
    s2 = sb[0] + sb[1] + sb[2] + sb[3];
    float mu = s * (1.f / (float)D_);
    float var = s2 * (1.f / (float)D_) - mu * mu;
    float rs = rsqrtf(var + EPS_);
    float4 gg = ((const float4*)g1)[t], bbv = ((const float4*)b1)[t];
    float4 z4;
    z4.x = (v.x - mu) * rs * gg.x + bbv.x;
    z4.y = (v.y - mu) * rs * gg.y + bbv.y;
    z4.z = (v.z - mu) * rs * gg.z + bbv.z;
    z4.w = (v.w - mu) * rs * gg.w + bbv.w;
    ((float4*)(z1out + (size_t)b * D_))[t] = z4;
    *(float4*)&zr[4 * t] = z4;
    __syncthreads();
    const float step = 6.283185307179586f / (float)D_;
    {
        float ar = 0.f, ai = 0.f;
        for (int n = sub; n < D_; n += 16) {
            int idx = (m * n) & (D_ - 1);
            float sn, cs;
            __sincosf(step * (float)idx, &sn, &cs);
            float z = zr[n];
            ar = fmaf(z, cs, ar); ai = fmaf(-z, sn, ai);
        }
#pragma unroll
        for (int o = 8; o > 0; o >>= 1) { ar += __shfl_xor(ar, o, 16); ai += __shfl_xor(ai, o, 16); }
        if (sub == 0) {
            cre[m] = (fre[m] * ar - fim[m] * ai) * (1.f / (float)D_);
            cim[m] = (fre[m] * ai + fim[m] * ar) * (1.f / (float)D_);
        }
    }
    __syncthreads();
    for (int n = t; n < D_; n += 256) {
        float acc = 0.f;
#pragma unroll
        for (int mm = 0; mm < MODES_; ++mm) {
            int idx = (mm * n) & (D_ - 1);
            float sn, cs;
            __sincosf(step * (float)idx, &sn, &cs);
            acc += cre[mm] * cs - cim[mm] * sn;
        }
        zspout[(size_t)b * D_ + n] = acc;
    }
}

// ---------------- LN2 + gate mix -> z3 ----------------
__global__ void k_ln2gate(const float* __restrict__ zprev, const float* __restrict__ g2,
                          const float* __restrict__ b2v, const float* __restrict__ gate,
                          float* __restrict__ ws) {
    int b = blockIdx.x, t = threadIdx.x, w = t >> 6, l = t & 63;
    float4 v = ((const float4*)(ws + OFF_R2 + (size_t)b * D_))[t];
    float s = v.x + v.y + v.z + v.w;
    float s2 = v.x * v.x + v.y * v.y + v.z * v.z + v.w * v.w;
    __shared__ float sa[4], sb[4];
#pragma unroll
    for (int o = 32; o > 0; o >>= 1) { s += __shfl_xor(s, o); s2 += __shfl_xor(s2, o); }
    if (l == 0) { sa[w] = s; sb[w] = s2; }
    __syncthreads();
    s = sa[0] + sa[1] + sa[2] + sa[3];
    s2 = sb[0] + sb[1] + sb[2] + sb[3];
    float mu = s * (1.f / (float)D_);
    float var = s2 * (1.f / (float)D_) - mu * mu;
    float rs = rsqrtf(var + EPS_);
    float4 gg = ((const float4*)g2)[t], bb = ((const float4*)b2v)[t];
    float gsig = 1.f / (1.f + __expf(-gate[0]));
    float4 zp = ((const float4*)(zprev + (size_t)b * D_))[t];
    float4 z3;
    z3.x = gsig * ((v.x - mu) * rs * gg.x + bb.x) + (1.f - gsig) * zp.x;
    z3.y = gsig * ((v.y - mu) * rs * gg.y + bb.y) + (1.f - gsig) * zp.y;
    z3.z = gsig * ((v.z - mu) * rs * gg.z + bb.z) + (1.f - gsig) * zp.z;
    z3.w = gsig * ((v.w - mu) * rs * gg.w + bb.w) + (1.f - gsig) * zp.w;
    ((float4*)(ws + OFF_Z3 + (size_t)b * D_))[t] = z3;
}

// ---------------- batchnorm over B per column ----------------
__global__ void k_bn(const float* __restrict__ bng, const float* __restrict__ bnb,
                     const float* __restrict__ z3, float* __restrict__ out) {
    int d = blockIdx.x * 256 + threadIdx.x;
    float vals[B_];
    float s = 0.f, s2 = 0.f;
#pragma unroll
    for (int b = 0; b < B_; ++b) {
        float v = z3[(size_t)b * D_ + d];
        vals[b] = v; s += v; s2 = fmaf(v, v, s2);
    }
    float mu = s * (1.f / (float)B_);
    float var = s2 * (1.f / (float)B_) - mu * mu;
    float rs = rsqrtf(var + EPS_);
    float gg = bng[d], bb = bnb[d];
#pragma unroll
    for (int b = 0; b < B_; ++b) out[(size_t)b * D_ + d] = (vals[b] - mu) * rs * gg + bb;
}

extern "C" void kernel_launch(void* const* d_in, const int* in_sizes, int n_in,
                              void* d_out, int out_size, void* d_ws, size_t ws_size,
                              hipStream_t stream) {
    const float* x_feat = (const float*)d_in[0];
    const float* z_prev = (const float*)d_in[1];
    const float* ipw    = (const float*)d_in[2];
    const float* ipb    = (const float*)d_in[3];
    const float* wout   = (const float*)d_in[4];
    const float* bout   = (const float*)d_in[5];
    const float* ln1g   = (const float*)d_in[6];
    const float* ln1b   = (const float*)d_in[7];
    const float* ln2g   = (const float*)d_in[8];
    const float* ln2b   = (const float*)d_in[9];
    const float* sreal  = (const float*)d_in[10];
    const float* simag  = (const float*)d_in[11];
    const float* pw     = (const float*)d_in[12];
    const float* pb     = (const float*)d_in[13];
    const float* bng    = (const float*)d_in[14];
    const float* bnb    = (const float*)d_in[15];
    const float* gate   = (const float*)d_in[16];
    const float* sattn  = (const float*)d_in[17];
    const float* sden   = (const float*)d_in[18];
    float* ws  = (float*)d_ws;
    float* out = (float*)d_out;
    unsigned short* qkbf  = (unsigned short*)(ws + OFF_QKBF);
    unsigned short* partp = (unsigned short*)(ws + OFF_PART_F);

    k_q<<<B_ * 4, 256, 0, stream>>>(z_prev, ipw, ipb, ws + OFF_Q, ws + OFF_CK);
    k_qkc<<<H_ * 16, 256, 0, stream>>>(ipw, ws + OFF_Q, qkbf);
    k_attn<<<B_ * NSPLIT_, 256, 0, stream>>>(x_feat, qkbf, ws + OFF_CK, partp, ws + OFF_ML);
    k_ctx2<<<B_ * 4, 256, 0, stream>>>(ipw, ipb, partp, ws + OFF_ML, ws + OFF_CTX);
    k_proj_res<<<B_ * 4, 256, 0, stream>>>(wout, bout, sattn, z_prev, ws + OFF_CTX, ws + OFF_R1);
    k_lnspec<<<B_, 256, 0, stream>>>(ws + OFF_R1, ln1g, ln1b, sreal, simag,
                                     ws + OFF_Z1, ws + OFF_ZSP);
    k_proj_res<<<B_ * 4, 256, 0, stream>>>(pw, pb, sden, ws + OFF_Z1, ws + OFF_ZSP, ws + OFF_R2);
    k_ln2gate<<<B_, 256, 0, stream>>>(z_prev, ln2g, ln2b, gate, ws);
    k_bn<<<D_ / 256, 256, 0, stream>>>(bng, bnb, ws + OFF_Z3, out);
}

// Round 17
// 223.695 us; speedup vs baseline: 1.0263x; 1.0174x over previous
//
#include <hip/hip_runtime.h>
#include <hip/hip_bf16.h>

#define B_ 32
#define S_ 2048
#define D_ 1024
#define H_ 16
#define HD_ 64
#define MODES_ 16
#define EPS_ 1e-5f

#define NSPLIT_ 16
#define RPB_ 128        // rows per block (S / NSPLIT)
#define RPI_ 16         // rows per iteration
#define NIT_ (RPB_ / RPI_)

// workspace float offsets
#define OFF_CK      32            // B*H = 512
#define OFF_Q       1024          // B*D = 32768 fp32
#define OFF_QKBF    33792         // B*H*D bf16 = 262144 float-equiv
#define OFF_ML      295936        // 2 * NSPLIT*B*H = 16384 floats
#define ML_L_OFF    8192
#define OFF_PART_F  312320        // bf16 partials: NSPLIT*B*H*D ushorts = 4194304 float-equiv
#define OFF_CTX     4506624       // B*D
#define OFF_R1      4539392
#define OFF_Z1      4572160
#define OFF_ZSP     4604928
#define OFF_R2      4637696
#define OFF_Z3      4670464

typedef __attribute__((ext_vector_type(8))) short short8v;
typedef __attribute__((ext_vector_type(4))) float f32x4;

static __device__ inline ushort2 f2bf2(float a, float b) {
    __hip_bfloat162 h = __float22bfloat162_rn(make_float2(a, b));
    union { __hip_bfloat162 h; ushort2 u; } v; v.h = h; return v.u;
}
static __device__ inline unsigned short f2bf(float a) {
    __hip_bfloat16 h = __float2bfloat16(a);
    union { __hip_bfloat16 h; unsigned short u; } v; v.h = h; return v.u;
}
static __device__ inline float bf2f(unsigned s) {
    union { unsigned u; float f; } v; v.u = s << 16;
    return v.f;
}

// ---------------- q[b,n] = z_prev[b,:].Wq[n,:] + bq[n] ; ck[b,h] = q.bk ----------------
__global__ void k_q(const float* __restrict__ zprev, const float* __restrict__ ipw,
                    const float* __restrict__ ipb, float* __restrict__ q_out,
                    float* __restrict__ ck_out) {
    int b = blockIdx.x >> 2, nc = blockIdx.x & 3;
    __shared__ float zr[D_];
    int t = threadIdx.x;
    for (int i = t; i < D_; i += 256) zr[i] = zprev[(size_t)b * D_ + i];
    __syncthreads();
    int n = nc * 256 + t;
    const float4* wr = (const float4*)(ipw + (size_t)n * D_);
    float a0 = 0.f, a1 = 0.f, a2 = 0.f, a3 = 0.f;
    for (int k = 0; k < 256; k += 4) {
        float4 w0 = wr[k], w1 = wr[k + 1], w2 = wr[k + 2], w3 = wr[k + 3];
        float4 z0 = *(const float4*)&zr[4 * k];
        float4 z1 = *(const float4*)&zr[4 * k + 4];
        float4 z2 = *(const float4*)&zr[4 * k + 8];
        float4 z3 = *(const float4*)&zr[4 * k + 12];
        a0 = fmaf(z0.x, w0.x, a0); a0 = fmaf(z0.y, w0.y, a0); a0 = fmaf(z0.z, w0.z, a0); a0 = fmaf(z0.w, w0.w, a0);
        a1 = fmaf(z1.x, w1.x, a1); a1 = fmaf(z1.y, w1.y, a1); a1 = fmaf(z1.z, w1.z, a1); a1 = fmaf(z1.w, w1.w, a1);
        a2 = fmaf(z2.x, w2.x, a2); a2 = fmaf(z2.y, w2.y, a2); a2 = fmaf(z2.z, w2.z, a2); a2 = fmaf(z2.w, w2.w, a2);
        a3 = fmaf(z3.x, w3.x, a3); a3 = fmaf(z3.y, w3.y, a3); a3 = fmaf(z3.z, w3.z, a3); a3 = fmaf(z3.w, w3.w, a3);
    }
    float qv = (a0 + a1) + (a2 + a3) + ipb[n];
    q_out[(size_t)b * D_ + n] = qv;
    float cv = qv * ipb[D_ + n];
#pragma unroll
    for (int o = 32; o > 0; o >>= 1) cv += __shfl_xor(cv, o);
    if ((t & 63) == 0) ck_out[b * H_ + (n >> 6)] = cv;
}

// ---------------- qk[b,h,n] = sum_i q[b,h*64+i] * Wk[h*64+i, n] -> bf16 ----------------
__global__ void k_qkc(const float* __restrict__ ipw, const float* __restrict__ q_in,
                      unsigned short* __restrict__ qk_out) {
    int bid = blockIdx.x;
    int bc = bid & 3, nc = (bid >> 2) & 3, h = bid >> 4;
    int t = threadIdx.x;
    __shared__ float4 tile4[HD_ * 64];   // 64 rows x 256 cols = 64KB
    __shared__ float qall[8 * HD_];
    const float4* wk4 = (const float4*)(ipw + (size_t)D_ * D_);
#pragma unroll
    for (int j = 0; j < 16; ++j) {
        int lin4 = j * 256 + t;
        int i = lin4 >> 6, n4 = lin4 & 63;
        tile4[lin4] = wk4[(size_t)(h * HD_ + i) * 256 + nc * 64 + n4];
    }
#pragma unroll
    for (int j = 0; j < 2; ++j) {
        int idx = j * 256 + t;
        int bb = idx >> 6, i = idx & 63;
        qall[idx] = q_in[(size_t)(bc * 8 + bb) * D_ + h * HD_ + i];
    }
    __syncthreads();
    const float* tile = (const float*)tile4;
#pragma unroll
    for (int bb = 0; bb < 8; ++bb) {
        float a0 = 0.f, a1 = 0.f;
#pragma unroll
        for (int i = 0; i < HD_; i += 2) {
            a0 = fmaf(qall[bb * HD_ + i], tile[i * 256 + t], a0);
            a1 = fmaf(qall[bb * HD_ + i + 1], tile[(i + 1) * 256 + t], a1);
        }
        int b = bc * 8 + bb;
        qk_out[(size_t)(b * H_ + h) * D_ + nc * 256 + t] = f2bf(a0 + a1);
    }
}

// ---- fused attention, MFMA, dual-layout LDS: row-major xbuf (QK^T A-op) +
// ---- d-major xcol (PV B-op as single b128 per MFMA, no scalar gather) ----
__global__ __launch_bounds__(256, 2) void k_attn(const float* __restrict__ xfeat,
        const unsigned short* __restrict__ qkbf, const float* __restrict__ ck,
        unsigned short* __restrict__ part, float* __restrict__ ml) {
    int bid = blockIdx.x;
    int c = bid & (NSPLIT_ - 1), b = bid >> 4;
    int t = threadIdx.x, w = t >> 6, l = t & 63;
    __shared__ unsigned char xbuf[RPI_ * 2048];     // 32KB bf16 X rows, XOR-swizzled
    __shared__ unsigned char xcol[D_ * RPI_ * 2];   // 32KB bf16 X cols (d-major, slot-XOR)
    __shared__ float Sred[4][RPI_][17];             // padded
    __shared__ unsigned short Pt[16][32];           // P^T bf16; cols 16..31 stay ZERO
    __shared__ float mh[16], lh[16], fh[16], ckl[16];

    if (t < 16) { mh[t] = -1e30f; lh[t] = 0.f; ckl[t] = ck[b * H_ + t]; }
    // zero the padded upper-K half of Pt once (cols 16..31)
    {
        int h = t >> 4, s = 16 + (t & 15);
        Pt[h][s] = 0;
    }

    f32x4 acc[16];
#pragma unroll
    for (int nt = 0; nt < 16; ++nt) acc[nt] = (f32x4){0.f, 0.f, 0.f, 0.f};

    int hr = l & 15, kg = l >> 4;
    // hoist qk B-fragments (loop-invariant): 8 x 16B = 32 VGPRs
    const unsigned short* qkb = qkbf + ((size_t)(b * H_ + hr) << 10);
    short8v qfrag[8];
#pragma unroll
    for (int ks = 0; ks < 8; ++ks)
        qfrag[ks] = *(const short8v*)(qkb + w * 256 + ks * 32 + kg * 8);

    for (int it = 0; it < NIT_; ++it) {
        __syncthreads();
        // ---- stage A: 16 rows fp32 -> bf16 row-major swizzled LDS ----
        {
            const float4* src = (const float4*)(xfeat + ((size_t)b * S_ + c * RPB_ + it * RPI_) * D_);
#pragma unroll
            for (int j = 0; j < 16; ++j) {
                int idx = j * 256 + t;
                float4 v = src[idx];
                int row = idx >> 8, dq = idx & 255;
                unsigned off = (unsigned)(row * 2048 + dq * 8) ^ (unsigned)((row & 7) << 4);
                ushort2 lo = f2bf2(v.x, v.y), hi = f2bf2(v.z, v.w);
                ushort4 u; u.x = lo.x; u.y = lo.y; u.z = hi.x; u.w = hi.y;
                *(ushort4*)(xbuf + off) = u;
            }
        }
        __syncthreads();
        // ---- phase 1: S = X . qk^T ----
        {
            f32x4 s0 = {0.f, 0.f, 0.f, 0.f};
#pragma unroll
            for (int ks = 0; ks < 8; ++ks) {
                int k = w * 256 + ks * 32 + kg * 8;
                unsigned off0 = (unsigned)(hr * 2048 + k * 2) ^ (unsigned)((hr & 7) << 4);
                short8v a0 = *(const short8v*)(xbuf + off0);
                s0 = __builtin_amdgcn_mfma_f32_16x16x32_bf16(a0, qfrag[ks], s0, 0, 0, 0);
            }
            int rbase = kg * 4;
#pragma unroll
            for (int r = 0; r < 4; ++r) Sred[w][rbase + r][hr] = s0[r];
        }
        // ---- stage B (overlaps phase 1): transpose xbuf -> xcol ----
        {
#pragma unroll
            for (int i = 0; i < 16; ++i) {
                int rg = i & 3, d = (i >> 2) * 256 + t;
                unsigned cb = (unsigned)((d >> 2) * 8) + (unsigned)((d & 3) * 2);
                int r0 = rg * 4;
                unsigned short v0 = *(const unsigned short*)(xbuf + (((unsigned)((r0 + 0) * 2048) + cb) ^ (unsigned)(((r0 + 0) & 7) << 4)));
                unsigned short v1 = *(const unsigned short*)(xbuf + (((unsigned)((r0 + 1) * 2048) + cb) ^ (unsigned)(((r0 + 1) & 7) << 4)));
                unsigned short v2 = *(const unsigned short*)(xbuf + (((unsigned)((r0 + 2) * 2048) + cb) ^ (unsigned)(((r0 + 2) & 7) << 4)));
                unsigned short v3 = *(const unsigned short*)(xbuf + (((unsigned)((r0 + 3) * 2048) + cb) ^ (unsigned)(((r0 + 3) & 7) << 4)));
                ushort4 u; u.x = v0; u.y = v1; u.z = v2; u.w = v3;
                unsigned slot = (unsigned)((rg >> 1) ^ ((d >> 2) & 1));
                unsigned coff = (unsigned)(d * 32) + slot * 16 + (unsigned)((rg & 1) * 8);
                *(ushort4*)(xcol + coff) = u;
            }
        }
        __syncthreads();
        // ---- phase 2: softmax (one thread per (h,row)), online m/l across iters ----
        {
            int h = t >> 4, i16 = t & 15;
            float sv0 = Sred[0][i16][h] + Sred[1][i16][h] + Sred[2][i16][h] + Sred[3][i16][h];
            float s0 = (sv0 + ckl[h]) * 0.125f;
            float mm = s0;
#pragma unroll
            for (int o = 8; o > 0; o >>= 1) mm = fmaxf(mm, __shfl_xor(mm, o, 16));
            float mold = mh[h];
            float mnew = fmaxf(mold, mm);
            float p0 = __expf(s0 - mnew);
            Pt[h][i16] = f2bf(p0);
            float ps = p0;
#pragma unroll
            for (int o = 8; o > 0; o >>= 1) ps += __shfl_xor(ps, o, 16);
            if (i16 == 0) {
                float f = __expf(mold - mnew);
                fh[h] = f; lh[h] = lh[h] * f + ps; mh[h] = mnew;
            }
        }
        __syncthreads();
        // ---- phase 3: rescale acc, then O += P^T . X via MFMA, B-op = 1 b128 ----
        {
            float f0 = fh[kg * 4 + 0], f1 = fh[kg * 4 + 1], f2 = fh[kg * 4 + 2], f3 = fh[kg * 4 + 3];
#pragma unroll
            for (int nt = 0; nt < 16; ++nt) {
                acc[nt][0] *= f0; acc[nt][1] *= f1; acc[nt][2] *= f2; acc[nt][3] *= f3;
            }
            short8v pa = *(const short8v*)(&Pt[hr][kg * 8]);   // kg>=2 -> zeros
#pragma unroll
            for (int nt = 0; nt < 16; ++nt) {
                int d = w * 256 + nt * 16 + hr;
                unsigned coff = (unsigned)(d * 32) + (unsigned)((((kg & 1) ^ ((d >> 2) & 1)) << 4));
                short8v bx = *(const short8v*)(xcol + coff);
                acc[nt] = __builtin_amdgcn_mfma_f32_16x16x32_bf16(pa, bx, acc[nt], 0, 0, 0);
            }
        }
    }
    // ---- store bf16 partials + m/l ----
    {
#pragma unroll
        for (int nt = 0; nt < 16; ++nt) {
            int d = w * 256 + nt * 16 + hr;
#pragma unroll
            for (int r = 0; r < 4; ++r) {
                int h = kg * 4 + r;
                part[(((size_t)(c * B_ + b) * H_ + h) << 10) + d] = f2bf(acc[nt][r]);
            }
        }
        if (t < 16) {
            ml[(size_t)(c * B_ + b) * H_ + t] = mh[t];
            ml[ML_L_OFF + (size_t)(c * B_ + b) * H_ + t] = lh[t];
        }
    }
}

// ------- combine partials (16 splits) + ctx GEMV (Wv), 512 thr, 2 threads/output -------
__global__ void k_ctx2(const float* __restrict__ ipw, const float* __restrict__ ipb,
                       const unsigned short* __restrict__ part, const float* __restrict__ ml,
                       float* __restrict__ ctx) {
    int b = blockIdx.x >> 2, nc = blockIdx.x & 3;
    int t = threadIdx.x;
    __shared__ float mls[4][16], lls[4][16], coef[4][16];
    __shared__ float xr[4 * D_];
    if (t < 64) {
        int h4 = t >> 4, c = t & 15;
        mls[h4][c] = ml[(size_t)(c * B_ + b) * H_ + nc * 4 + h4];
        lls[h4][c] = ml[ML_L_OFF + (size_t)(c * B_ + b) * H_ + nc * 4 + h4];
    }
    __syncthreads();
    if (t < 4) {
        float M = -1e30f;
        for (int c = 0; c < 16; ++c) M = fmaxf(M, mls[t][c]);
        float L = 0.f;
        for (int c = 0; c < 16; ++c) L += lls[t][c] * __expf(mls[t][c] - M);
        float invL = 1.f / L;
        for (int c = 0; c < 16; ++c) coef[t][c] = __expf(mls[t][c] - M) * invL;
    }
    __syncthreads();
    for (int idx = t * 2; idx < 4 * D_; idx += 1024) {
        int h4 = idx >> 10, d = idx & 1023;
        int h = nc * 4 + h4;
        float a0 = 0.f, a1 = 0.f;
        for (int c = 0; c < 16; ++c) {
            unsigned u = *(const unsigned*)&part[(((size_t)(c * B_ + b) * H_ + h) << 10) + d];
            float cf = coef[h4][c];
            a0 = fmaf(bf2f(u & 0xffffu), cf, a0);
            a1 = fmaf(bf2f(u >> 16), cf, a1);
        }
        xr[idx] = a0; xr[idx + 1] = a1;
    }
    __syncthreads();
    int n = nc * 256 + (t >> 1), half = t & 1;
    int hl = t >> 7;   // (n&255)>>6
    const float4* wr = (const float4*)(ipw + ((size_t)2 * D_ + n) * D_) + half * 128;
    const float4* xv4 = (const float4*)&xr[hl * D_] + half * 128;
    float a0 = 0.f, a1 = 0.f, a2 = 0.f, a3 = 0.f;
    for (int k = 0; k < 128; k += 4) {
        float4 w0 = wr[k], w1 = wr[k + 1], w2 = wr[k + 2], w3 = wr[k + 3];
        float4 x0 = xv4[k], x1 = xv4[k + 1], x2 = xv4[k + 2], x3 = xv4[k + 3];
        a0 = fmaf(w0.x, x0.x, a0); a0 = fmaf(w0.y, x0.y, a0); a0 = fmaf(w0.z, x0.z, a0); a0 = fmaf(w0.w, x0.w, a0);
        a1 = fmaf(w1.x, x1.x, a1); a1 = fmaf(w1.y, x1.y, a1); a1 = fmaf(w1.z, x1.z, a1); a1 = fmaf(w1.w, x1.w, a1);
        a2 = fmaf(w2.x, x2.x, a2); a2 = fmaf(w2.y, x2.y, a2); a2 = fmaf(w2.z, x2.z, a2); a2 = fmaf(w2.w, x2.w, a2);
        a3 = fmaf(w3.x, x3.x, a3); a3 = fmaf(w3.y, x3.y, a3); a3 = fmaf(w3.z, x3.z, a3); a3 = fmaf(w3.w, x3.w, a3);
    }
    float acc = (a0 + a1) + (a2 + a3);
    acc += __shfl_xor(acc, 1);
    if (half == 0) ctx[(size_t)b * D_ + n] = acc + ipb[2 * D_ + n];
}

// ------- out = resid + scale*(invec @ W.T + bias), 512 thr, 2 threads/output -------
__global__ void k_proj_res(const float* __restrict__ wmat, const float* __restrict__ bias,
                           const float* __restrict__ scale, const float* __restrict__ resid,
                           const float* __restrict__ invec, float* __restrict__ outvec) {
    int b = blockIdx.x >> 2, nc = blockIdx.x & 3;
    __shared__ float cx[D_];
    int t = threadIdx.x;
    for (int i = t; i < D_; i += 512) cx[i] = invec[(size_t)b * D_ + i];
    __syncthreads();
    int n = nc * 256 + (t >> 1), half = t & 1;
    const float4* wr = (const float4*)(wmat + (size_t)n * D_) + half * 128;
    const float4* cv4 = (const float4*)cx + half * 128;
    float a0 = 0.f, a1 = 0.f, a2 = 0.f, a3 = 0.f;
    for (int k = 0; k < 128; k += 4) {
        float4 w0 = wr[k], w1 = wr[k + 1], w2 = wr[k + 2], w3 = wr[k + 3];
        float4 c0 = cv4[k], c1 = cv4[k + 1], c2 = cv4[k + 2], c3 = cv4[k + 3];
        a0 = fmaf(w0.x, c0.x, a0); a0 = fmaf(w0.y, c0.y, a0); a0 = fmaf(w0.z, c0.z, a0); a0 = fmaf(w0.w, c0.w, a0);
        a1 = fmaf(w1.x, c1.x, a1); a1 = fmaf(w1.y, c1.y, a1); a1 = fmaf(w1.z, c1.z, a1); a1 = fmaf(w1.w, c1.w, a1);
        a2 = fmaf(w2.x, c2.x, a2); a2 = fmaf(w2.y, c2.y, a2); a2 = fmaf(w2.z, c2.z, a2); a2 = fmaf(w2.w, c2.w, a2);
        a3 = fmaf(w3.x, c3.x, a3); a3 = fmaf(w3.y, c3.y, a3); a3 = fmaf(w3.z, c3.z, a3); a3 = fmaf(w3.w, c3.w, a3);
    }
    float acc = (a0 + a1) + (a2 + a3);
    acc += __shfl_xor(acc, 1);
    if (half == 0)
        outvec[(size_t)b * D_ + n] = resid[(size_t)b * D_ + n] + scale[0] * (acc + bias[n]);
}

// ---------------- fused LN1 + spectral (filt, DFT, filter, synthesize) ----------------
__global__ void k_lnspec(const float* __restrict__ r1, const float* __restrict__ g1,
                         const float* __restrict__ b1, const float* __restrict__ sreal,
                         const float* __restrict__ simag, float* __restrict__ z1out,
                         float* __restrict__ zspout) {
    int b = blockIdx.x, t = threadIdx.x, w = t >> 6, l = t & 63;
    __shared__ float zr[D_];
    __shared__ float fre[MODES_], fim[MODES_];
    __shared__ float cre[MODES_], cim[MODES_];
    __shared__ float sa[4], sb[4];
    float4 v = ((const float4*)(r1 + (size_t)b * D_))[t];
    float s = v.x + v.y + v.z + v.w;
    float s2 = v.x * v.x + v.y * v.y + v.z * v.z + v.w * v.w;
#pragma unroll
    for (int o = 32; o > 0; o >>= 1) { s += __shfl_xor(s, o); s2 += __shfl_xor(s2, o); }
    if (l == 0) { sa[w] = s; sb[w] = s2; }
    int m = t >> 4, sub = t & 15;
    {
        float ar = 0.f, ai = 0.f;
        for (int k = sub; k < D_; k += 16) { ar += sreal[m * D_ + k]; ai += simag[m * D_ + k]; }
#pragma unroll
        for (int o = 8; o > 0; o >>= 1) { ar += __shfl_xor(ar, o, 16); ai += __shfl_xor(ai, o, 16); }
        if (sub == 0) { fre[m] = ar * (1.f / (float)D_); fim[m] = ai * (1.f / (float)D_); }
    }
    __syncthreads();
    s = sa[0] + sa[1] + sa[2] + sa[3];
    s2 = sb[0] + sb[1] + sb[2] + sb[3];
    float mu = s * (1.f / (float)D_);
    float var = s2 * (1.f / (float)D_) - mu * mu;
    float rs = rsqrtf(var + EPS_);
    float4 gg = ((const float4*)g1)[t], bbv = ((const float4*)b1)[t];
    float4 z4;
    z4.x = (v.x - mu) * rs * gg.x + bbv.x;
    z4.y = (v.y - mu) * rs * gg.y + bbv.y;
    z4.z = (v.z - mu) * rs * gg.z + bbv.z;
    z4.w = (v.w - mu) * rs * gg.w + bbv.w;
    ((float4*)(z1out + (size_t)b * D_))[t] = z4;
    *(float4*)&zr[4 * t] = z4;
    __syncthreads();
    const float step = 6.283185307179586f / (float)D_;
    {
        float ar = 0.f, ai = 0.f;
        for (int n = sub; n < D_; n += 16) {
            int idx = (m * n) & (D_ - 1);
            float sn, cs;
            __sincosf(step * (float)idx, &sn, &cs);
            float z = zr[n];
            ar = fmaf(z, cs, ar); ai = fmaf(-z, sn, ai);
        }
#pragma unroll
        for (int o = 8; o > 0; o >>= 1) { ar += __shfl_xor(ar, o, 16); ai += __shfl_xor(ai, o, 16); }
        if (sub == 0) {
            cre[m] = (fre[m] * ar - fim[m] * ai) * (1.f / (float)D_);
            cim[m] = (fre[m] * ai + fim[m] * ar) * (1.f / (float)D_);
        }
    }
    __syncthreads();
    for (int n = t; n < D_; n += 256) {
        float acc = 0.f;
#pragma unroll
        for (int mm = 0; mm < MODES_; ++mm) {
            int idx = (mm * n) & (D_ - 1);
            float sn, cs;
            __sincosf(step * (float)idx, &sn, &cs);
            acc += cre[mm] * cs - cim[mm] * sn;
        }
        zspout[(size_t)b * D_ + n] = acc;
    }
}

// ---------------- LN2 + gate mix -> z3 ----------------
__global__ void k_ln2gate(const float* __restrict__ zprev, const float* __restrict__ g2,
                          const float* __restrict__ b2v, const float* __restrict__ gate,
                          float* __restrict__ ws) {
    int b = blockIdx.x, t = threadIdx.x, w = t >> 6, l = t & 63;
    float4 v = ((const float4*)(ws + OFF_R2 + (size_t)b * D_))[t];
    float s = v.x + v.y + v.z + v.w;
    float s2 = v.x * v.x + v.y * v.y + v.z * v.z + v.w * v.w;
    __shared__ float sa[4], sb[4];
#pragma unroll
    for (int o = 32; o > 0; o >>= 1) { s += __shfl_xor(s, o); s2 += __shfl_xor(s2, o); }
    if (l == 0) { sa[w] = s; sb[w] = s2; }
    __syncthreads();
    s = sa[0] + sa[1] + sa[2] + sa[3];
    s2 = sb[0] + sb[1] + sb[2] + sb[3];
    float mu = s * (1.f / (float)D_);
    float var = s2 * (1.f / (float)D_) - mu * mu;
    float rs = rsqrtf(var + EPS_);
    float4 gg = ((const float4*)g2)[t], bb = ((const float4*)b2v)[t];
    float gsig = 1.f / (1.f + __expf(-gate[0]));
    float4 zp = ((const float4*)(zprev + (size_t)b * D_))[t];
    float4 z3;
    z3.x = gsig * ((v.x - mu) * rs * gg.x + bb.x) + (1.f - gsig) * zp.x;
    z3.y = gsig * ((v.y - mu) * rs * gg.y + bb.y) + (1.f - gsig) * zp.y;
    z3.z = gsig * ((v.z - mu) * rs * gg.z + bb.z) + (1.f - gsig) * zp.z;
    z3.w = gsig * ((v.w - mu) * rs * gg.w + bb.w) + (1.f - gsig) * zp.w;
    ((float4*)(ws + OFF_Z3 + (size_t)b * D_))[t] = z3;
}

// ---------------- batchnorm over B per column ----------------
__global__ void k_bn(const float* __restrict__ bng, const float* __restrict__ bnb,
                     const float* __restrict__ z3, float* __restrict__ out) {
    int d = blockIdx.x * 256 + threadIdx.x;
    float vals[B_];
    float s = 0.f, s2 = 0.f;
#pragma unroll
    for (int b = 0; b < B_; ++b) {
        float v = z3[(size_t)b * D_ + d];
        vals[b] = v; s += v; s2 = fmaf(v, v, s2);
    }
    float mu = s * (1.f / (float)B_);
    float var = s2 * (1.f / (float)B_) - mu * mu;
    float rs = rsqrtf(var + EPS_);
    float gg = bng[d], bb = bnb[d];
#pragma unroll
    for (int b = 0; b < B_; ++b) out[(size_t)b * D_ + d] = (vals[b] - mu) * rs * gg + bb;
}

extern "C" void kernel_launch(void* const* d_in, const int* in_sizes, int n_in,
                              void* d_out, int out_size, void* d_ws, size_t ws_size,
                              hipStream_t stream) {
    const float* x_feat = (const float*)d_in[0];
    const float* z_prev = (const float*)d_in[1];
    const float* ipw    = (const float*)d_in[2];
    const float* ipb    = (const float*)d_in[3];
    const float* wout   = (const float*)d_in[4];
    const float* bout   = (const float*)d_in[5];
    const float* ln1g   = (const float*)d_in[6];
    const float* ln1b   = (const float*)d_in[7];
    const float* ln2g   = (const float*)d_in[8];
    const float* ln2b   = (const float*)d_in[9];
    const float* sreal  = (const float*)d_in[10];
    const float* simag  = (const float*)d_in[11];
    const float* pw     = (const float*)d_in[12];
    const float* pb     = (const float*)d_in[13];
    const float* bng    = (const float*)d_in[14];
    const float* bnb    = (const float*)d_in[15];
    const float* gate   = (const float*)d_in[16];
    const float* sattn  = (const float*)d_in[17];
    const float* sden   = (const float*)d_in[18];
    float* ws  = (float*)d_ws;
    float* out = (float*)d_out;
    unsigned short* qkbf  = (unsigned short*)(ws + OFF_QKBF);
    unsigned short* partp = (unsigned short*)(ws + OFF_PART_F);

    k_q<<<B_ * 4, 256, 0, stream>>>(z_prev, ipw, ipb, ws + OFF_Q, ws + OFF_CK);
    k_qkc<<<H_ * 16, 256, 0, stream>>>(ipw, ws + OFF_Q, qkbf);
    k_attn<<<B_ * NSPLIT_, 256, 0, stream>>>(x_feat, qkbf, ws + OFF_CK, partp, ws + OFF_ML);
    k_ctx2<<<B_ * 4, 512, 0, stream>>>(ipw, ipb, partp, ws + OFF_ML, ws + OFF_CTX);
    k_proj_res<<<B_ * 4, 512, 0, stream>>>(wout, bout, sattn, z_prev, ws + OFF_CTX, ws + OFF_R1);
    k_lnspec<<<B_, 256, 0, stream>>>(ws + OFF_R1, ln1g, ln1b, sreal, simag,
                                     ws + OFF_Z1, ws + OFF_ZSP);
    k_proj_res<<<B_ * 4, 512, 0, stream>>>(pw, pb, sden, ws + OFF_Z1, ws + OFF_ZSP, ws + OFF_R2);
    k_ln2gate<<<B_, 256, 0, stream>>>(z_prev, ln2g, ln2b, gate, ws);
    k_bn<<<D_ / 256, 256, 0, stream>>>(bng, bnb, ws + OFF_Z3, out);
}